// Round 2
// baseline (2711.008 us; speedup 1.0000x reference)
//
#include <hip/hip_runtime.h>
#include <math.h>

#define NN   40000
#define EE   640000
#define HID  32
#define FEAT 16
#define LAB  4
#define TT   8
#define DIN  53   // FEAT + LAB + HID + 1

// ---------------- CSR build ----------------

__global__ __launch_bounds__(256) void zero_i32(int* __restrict__ p, int n) {
    int i = blockIdx.x * 256 + threadIdx.x;
    if (i < n) p[i] = 0;
}

__global__ __launch_bounds__(256) void hist_kernel(const int* __restrict__ dst,
                                                   int* __restrict__ deg) {
    int e = blockIdx.x * 256 + threadIdx.x;
    if (e < EE) atomicAdd(&deg[dst[e]], 1);
}

// single-block exclusive scan over deg -> row_ptr (N+1)
__global__ __launch_bounds__(1024) void scan_kernel(const int* __restrict__ deg,
                                                    int* __restrict__ row_ptr) {
    __shared__ int sm[1024];
    int carry = 0;
    if (threadIdx.x == 0) row_ptr[0] = 0;
    for (int base = 0; base < NN; base += 1024) {
        int i = base + threadIdx.x;
        int v = (i < NN) ? deg[i] : 0;
        sm[threadIdx.x] = v;
        __syncthreads();
        for (int off = 1; off < 1024; off <<= 1) {
            int t = (threadIdx.x >= off) ? sm[threadIdx.x - off] : 0;
            __syncthreads();
            sm[threadIdx.x] += t;
            __syncthreads();
        }
        if (i < NN) row_ptr[i + 1] = carry + sm[threadIdx.x];
        carry += sm[1023];
        __syncthreads();
    }
}

__global__ __launch_bounds__(256) void scatter_kernel(const int* __restrict__ src,
                                                      const int* __restrict__ dst,
                                                      const int* __restrict__ row_ptr,
                                                      int* __restrict__ cursor,
                                                      int* __restrict__ csr_src) {
    int e = blockIdx.x * 256 + threadIdx.x;
    if (e < EE) {
        int d = dst[e];
        int pos = atomicAdd(&cursor[d], 1);
        csr_src[row_ptr[d] + pos] = src[e];
    }
}

// ---------------- state init ----------------

__global__ __launch_bounds__(256) void init_kernel(const float* __restrict__ x0,
                                                   const float* __restrict__ mask,
                                                   float* __restrict__ hidden,
                                                   float* __restrict__ x2) {
    int i = blockIdx.x * 256 + threadIdx.x;
    if (i < NN * HID) hidden[i] = 1.0f;
    if (i < NN * FEAT) {
        int node = i >> 4;
        x2[i] = (mask[node] > 0.5f) ? x0[i] : 0.0f;
    }
}

// ---------------- dense: xl = inp@Wl.T+bl, xr = inp@Wr.T+br ----------------
// LAYOUT 0: inp = [feat16, mask, labels4, h32]   (h optionally multiplied by hmul)
// LAYOUT 1: inp = [feat16, mask, h32, labels4]

template <int LAYOUT, bool HMUL>
__global__ __launch_bounds__(256) void dense_kernel(const float* __restrict__ feat,
                                                    const float* __restrict__ mask,
                                                    const float* __restrict__ labels,
                                                    const float* __restrict__ hsrc,
                                                    const float* __restrict__ hmul,
                                                    const float* __restrict__ Wl,
                                                    const float* __restrict__ bl,
                                                    const float* __restrict__ Wr,
                                                    const float* __restrict__ br,
                                                    float* __restrict__ xl,
                                                    float* __restrict__ xr) {
    __shared__ float Wl_s[HID * DIN];
    __shared__ float Wr_s[HID * DIN];
    __shared__ float inp_s[8][DIN];
    for (int idx = threadIdx.x; idx < HID * DIN; idx += 256) {
        Wl_s[idx] = Wl[idx];
        Wr_s[idx] = Wr[idx];
    }
    int ni = threadIdx.x >> 5, k = threadIdx.x & 31;
    int node = blockIdx.x * 8 + ni;
    for (int i = k; i < DIN; i += 32) {
        float v;
        if (LAYOUT == 0) {
            if (i < 16)       v = feat[node * 16 + i];
            else if (i == 16) v = mask[node];
            else if (i < 21)  v = labels[node * 4 + (i - 17)];
            else {
                v = hsrc[node * 32 + (i - 21)];
                if (HMUL) v *= hmul[node * 32 + (i - 21)];
            }
        } else {
            if (i < 16)       v = feat[node * 16 + i];
            else if (i == 16) v = mask[node];
            else if (i < 49)  v = hsrc[node * 32 + (i - 17)];
            else              v = labels[node * 4 + (i - 49)];
        }
        inp_s[ni][i] = v;
    }
    __syncthreads();
    float al = bl[k], ar = br[k];
    const float* wlr = &Wl_s[k * DIN];
    const float* wrr = &Wr_s[k * DIN];
#pragma unroll
    for (int i = 0; i < DIN; ++i) {
        float xv = inp_s[ni][i];
        al += xv * wlr[i];
        ar += xv * wrr[i];
    }
    xl[node * 32 + k] = al;
    xr[node * 32 + k] = ar;
}

// ---------------- GATv2 conv, CSR per-node online softmax ----------------
// ACT: 0 = sigmoid, 1 = tanh, 2 = relu
template <int ACT>
__global__ __launch_bounds__(256) void conv_kernel(const int* __restrict__ row_ptr,
                                                   const int* __restrict__ csr_src,
                                                   const float* __restrict__ xl,
                                                   const float* __restrict__ xr,
                                                   const float* __restrict__ att,
                                                   const float* __restrict__ bconv,
                                                   float* __restrict__ out) {
    int node = blockIdx.x * 8 + (threadIdx.x >> 5);
    int k = threadIdx.x & 31;
    float attk = att[k];
    float xrk = xr[node * 32 + k];
    int beg = row_ptr[node], end = row_ptr[node + 1];
    float m = -INFINITY, den = 0.0f, acc = 0.0f;
    for (int p = beg; p < end; ++p) {
        int s = csr_src[p];
        float v = xl[s * 32 + k];
        float z = v + xrk;
        z = (z > 0.0f) ? z : 0.2f * z;
        float part = z * attk;
        part += __shfl_xor(part, 16);
        part += __shfl_xor(part, 8);
        part += __shfl_xor(part, 4);
        part += __shfl_xor(part, 2);
        part += __shfl_xor(part, 1);
        float e = part;
        if (e > m) {
            float sc = __expf(m - e);
            den *= sc;
            acc *= sc;
            m = e;
        }
        float a = __expf(e - m);
        den += a;
        acc += a * v;
    }
    float o = (den > 0.0f) ? acc / den : 0.0f;
    o += bconv[k];
    if (ACT == 0)      o = 1.0f / (1.0f + __expf(-o));
    else if (ACT == 1) o = tanhf(o);
    else               o = fmaxf(o, 0.0f);
    out[node * 32 + k] = o;
}

// ---------------- hidden update + y1/x1 ----------------

__global__ __launch_bounds__(256) void update_kernel(const float* __restrict__ g_update,
                                                     const float* __restrict__ g_cell,
                                                     float* __restrict__ hidden,
                                                     const float* __restrict__ x_t,
                                                     const float* __restrict__ mask,
                                                     const float* __restrict__ W1,
                                                     const float* __restrict__ b1,
                                                     float* __restrict__ x1) {
    __shared__ float hs[8][HID + 1];
    int ni = threadIdx.x >> 5, k = threadIdx.x & 31;
    int node = blockIdx.x * 8 + ni;
    float u = g_update[node * 32 + k];
    float c = g_cell[node * 32 + k];
    float h = hidden[node * 32 + k];
    float hn = u * h + (1.0f - u) * c;
    hidden[node * 32 + k] = hn;
    hs[ni][k] = hn;
    __syncthreads();
    if (k < 16) {
        float acc = b1[k];
        const float* w = &W1[k * 32];
#pragma unroll
        for (int j = 0; j < 32; ++j) acc += hs[ni][j] * w[j];
        float mv = mask[node];
        float xv = x_t[node * 16 + k];
        x1[node * 16 + k] = (mv > 0.5f) ? xv : acc;
    }
}

// ---------------- y2 / x2_new / out[t] ----------------

__global__ __launch_bounds__(256) void out_kernel(const float* __restrict__ s,
                                                  const float* __restrict__ hidden,
                                                  const float* __restrict__ W2,
                                                  const float* __restrict__ b2,
                                                  const float* __restrict__ x_t,
                                                  const float* __restrict__ mask,
                                                  float* __restrict__ x2,
                                                  float* __restrict__ out_t) {
    int ni = threadIdx.x >> 4, f = threadIdx.x & 15;
    int node = blockIdx.x * 16 + ni;
    float acc = b2[f];
    const float* srow = s + node * 32;
    const float* hrow = hidden + node * 32;
    const float* w = W2 + f * 64;
#pragma unroll
    for (int j = 0; j < 32; ++j) acc += srow[j] * w[j];
#pragma unroll
    for (int j = 0; j < 32; ++j) acc += hrow[j] * w[32 + j];
    float mv = mask[node];
    float xv = x_t[node * 16 + f];
    float r = (mv > 0.5f) ? xv : acc;
    x2[node * 16 + f] = r;
    out_t[node * 16 + f] = r;
}

// ---------------- launch ----------------

extern "C" void kernel_launch(void* const* d_in, const int* in_sizes, int n_in,
                              void* d_out, int out_size, void* d_ws, size_t ws_size,
                              hipStream_t stream) {
    const float* x      = (const float*)d_in[0];
    const float* mask   = (const float*)d_in[1];
    const float* labels = (const float*)d_in[2];
    const int*   src    = (const int*)d_in[3];
    const int*   dst    = src + EE;
    // d_in[4] = edge_weight: unused by the reference
    const float* Wl    = (const float*)d_in[5];
    const float* bl    = (const float*)d_in[6];
    const float* Wr    = (const float*)d_in[7];
    const float* br    = (const float*)d_in[8];
    const float* att   = (const float*)d_in[9];
    const float* bconv = (const float*)d_in[10];
    const float* W1    = (const float*)d_in[11];
    const float* b1    = (const float*)d_in[12];
    const float* W2    = (const float*)d_in[13];
    const float* b2    = (const float*)d_in[14];
    float* out = (float*)d_out;

    char* ws = (char*)d_ws;
    size_t off = 0;
    auto alloc = [&](size_t bytes) -> void* {
        void* p = ws + off;
        off = (off + bytes + 255) & ~(size_t)255;
        return p;
    };
    int*   row_ptr = (int*)alloc((NN + 1) * sizeof(int));
    int*   deg     = (int*)alloc(NN * sizeof(int));
    int*   csr_src = (int*)alloc(EE * sizeof(int));
    float* hidden  = (float*)alloc(NN * HID * sizeof(float));
    float* x2      = (float*)alloc(NN * FEAT * sizeof(float));
    float* xl      = (float*)alloc(NN * HID * sizeof(float));
    float* xr      = (float*)alloc(NN * HID * sizeof(float));
    float* g0      = (float*)alloc(NN * HID * sizeof(float));  // reset, later s
    float* g1      = (float*)alloc(NN * HID * sizeof(float));  // update
    float* g2      = (float*)alloc(NN * HID * sizeof(float));  // cell
    float* x1      = (float*)alloc(NN * FEAT * sizeof(float));

    const int WD = HID * DIN;

    // CSR build (dst is identical for every conv, build once per call)
    zero_i32<<<(NN + 255) / 256, 256, 0, stream>>>(deg, NN);
    hist_kernel<<<EE / 256, 256, 0, stream>>>(dst, deg);
    scan_kernel<<<1, 1024, 0, stream>>>(deg, row_ptr);
    zero_i32<<<(NN + 255) / 256, 256, 0, stream>>>(deg, NN);
    scatter_kernel<<<EE / 256, 256, 0, stream>>>(src, dst, row_ptr, deg, csr_src);
    init_kernel<<<NN * HID / 256, 256, 0, stream>>>(x, mask, hidden, x2);

    for (int t = 0; t < TT; ++t) {
        const float* xt = x + (size_t)t * NN * FEAT;
        float* out_t = out + (size_t)t * NN * FEAT;
        // gate 0: reset = sigmoid(gatv2(inp))
        dense_kernel<0, false><<<NN / 8, 256, 0, stream>>>(x2, mask, labels, hidden, nullptr,
            Wl + 0 * WD, bl + 0 * HID, Wr + 0 * WD, br + 0 * HID, xl, xr);
        conv_kernel<0><<<NN / 8, 256, 0, stream>>>(row_ptr, csr_src, xl, xr,
            att + 0 * HID, bconv + 0 * HID, g0);
        // gate 1: update = sigmoid(gatv2(inp))
        dense_kernel<0, false><<<NN / 8, 256, 0, stream>>>(x2, mask, labels, hidden, nullptr,
            Wl + 1 * WD, bl + 1 * HID, Wr + 1 * WD, br + 1 * HID, xl, xr);
        conv_kernel<0><<<NN / 8, 256, 0, stream>>>(row_ptr, csr_src, xl, xr,
            att + 1 * HID, bconv + 1 * HID, g1);
        // gate 2: cell = tanh(gatv2(cin)), cin's h-part = reset*hidden
        dense_kernel<0, true><<<NN / 8, 256, 0, stream>>>(x2, mask, labels, hidden, g0,
            Wl + 2 * WD, bl + 2 * HID, Wr + 2 * WD, br + 2 * HID, xl, xr);
        conv_kernel<1><<<NN / 8, 256, 0, stream>>>(row_ptr, csr_src, xl, xr,
            att + 2 * HID, bconv + 2 * HID, g2);
        // hidden = u*h + (1-u)*c;  y1 = hidden@W1.T+b1;  x1 = mask? x[t] : y1
        update_kernel<<<NN / 8, 256, 0, stream>>>(g1, g2, hidden, xt, mask, W1, b1, x1);
        // gate 3: s = relu(gatv2(ft2)), ft2 = [x1, mask, hidden, labels]
        dense_kernel<1, false><<<NN / 8, 256, 0, stream>>>(x1, mask, labels, hidden, nullptr,
            Wl + 3 * WD, bl + 3 * HID, Wr + 3 * WD, br + 3 * HID, xl, xr);
        conv_kernel<2><<<NN / 8, 256, 0, stream>>>(row_ptr, csr_src, xl, xr,
            att + 3 * HID, bconv + 3 * HID, g0);
        // y2 = [s,hidden]@W2.T+b2; x2 = mask? x[t] : y2; out[t] = x2
        out_kernel<<<NN / 16, 256, 0, stream>>>(g0, hidden, W2, b2, xt, mask, x2, out_t);
    }
}

// Round 4
// 1998.500 us; speedup vs baseline: 1.3565x; 1.3565x over previous
//
#include <hip/hip_runtime.h>
#include <math.h>

#define NN   40000
#define EE   640000
#define HID  32
#define FEAT 16
#define LAB  4
#define TT   8
#define DIN  53   // FEAT + LAB + HID + 1

// ---------------- CSR build ----------------

__global__ __launch_bounds__(256) void zero_i32(int* __restrict__ p, int n) {
    int i = blockIdx.x * 256 + threadIdx.x;
    if (i < n) p[i] = 0;
}

__global__ __launch_bounds__(256) void hist_kernel(const int* __restrict__ dst,
                                                   int* __restrict__ deg) {
    int e = blockIdx.x * 256 + threadIdx.x;
    if (e < EE) atomicAdd(&deg[dst[e]], 1);
}

// single-block exclusive scan over deg -> row_ptr (N+1), wave-shuffle based
__global__ __launch_bounds__(1024) void scan_kernel(const int* __restrict__ deg,
                                                    int* __restrict__ row_ptr) {
    __shared__ int wsum[16];
    __shared__ int chunk_total;
    int tid = threadIdx.x;
    int lane = tid & 63, wv = tid >> 6;
    int carry = 0;
    if (tid == 0) row_ptr[0] = 0;
    for (int base = 0; base < NN; base += 1024) {
        int i = base + tid;
        int v = (i < NN) ? deg[i] : 0;
        // wave inclusive scan
        #pragma unroll
        for (int o = 1; o < 64; o <<= 1) {
            int t = __shfl_up(v, o);
            if (lane >= o) v += t;
        }
        if (lane == 63) wsum[wv] = v;
        __syncthreads();
        if (tid < 16) {
            int s = wsum[tid];
            #pragma unroll
            for (int o = 1; o < 16; o <<= 1) {
                int t = __shfl_up(s, o);
                if (tid >= o) s += t;
            }
            wsum[tid] = s;
            if (tid == 15) chunk_total = s;
        }
        __syncthreads();
        int woff = (wv == 0) ? 0 : wsum[wv - 1];
        if (i < NN) row_ptr[i + 1] = carry + woff + v;
        carry += chunk_total;
        __syncthreads();
    }
}

__global__ __launch_bounds__(256) void scatter_kernel(const int* __restrict__ src,
                                                      const int* __restrict__ dst,
                                                      const int* __restrict__ row_ptr,
                                                      int* __restrict__ cursor,
                                                      int* __restrict__ csr_src) {
    int e = blockIdx.x * 256 + threadIdx.x;
    if (e < EE) {
        int d = dst[e];
        int pos = atomicAdd(&cursor[d], 1);
        csr_src[row_ptr[d] + pos] = src[e];
    }
}

// ---------------- state init ----------------

__global__ __launch_bounds__(256) void init_kernel(const float* __restrict__ x0,
                                                   const float* __restrict__ mask,
                                                   float* __restrict__ hidden,
                                                   float* __restrict__ x2) {
    int i = blockIdx.x * 256 + threadIdx.x;
    if (i < NN * HID) hidden[i] = 1.0f;
    if (i < NN * FEAT) {
        int node = i >> 4;
        x2[i] = (mask[node] > 0.5f) ? x0[i] : 0.0f;
    }
}

// ---------------- dense: xl = inp@Wl.T+bl, xr = inp@Wr.T+br ----------------
// inp = [feat16, mask, labels4, h32]   (h optionally multiplied by hmul)

template <bool HMUL>
__global__ __launch_bounds__(256) void dense_kernel(const float* __restrict__ feat,
                                                    const float* __restrict__ mask,
                                                    const float* __restrict__ labels,
                                                    const float* __restrict__ hsrc,
                                                    const float* __restrict__ hmul,
                                                    const float* __restrict__ Wl,
                                                    const float* __restrict__ bl,
                                                    const float* __restrict__ Wr,
                                                    const float* __restrict__ br,
                                                    float* __restrict__ xl,
                                                    float* __restrict__ xr) {
    __shared__ float Wl_s[HID * DIN];
    __shared__ float Wr_s[HID * DIN];
    __shared__ float inp_s[8][DIN];
    for (int idx = threadIdx.x; idx < HID * DIN; idx += 256) {
        Wl_s[idx] = Wl[idx];
        Wr_s[idx] = Wr[idx];
    }
    int ni = threadIdx.x >> 5, k = threadIdx.x & 31;
    int node = blockIdx.x * 8 + ni;
    for (int i = k; i < DIN; i += 32) {
        float v;
        if (i < 16)       v = feat[node * 16 + i];
        else if (i == 16) v = mask[node];
        else if (i < 21)  v = labels[node * 4 + (i - 17)];
        else {
            v = hsrc[node * 32 + (i - 21)];
            if (HMUL) v *= hmul[node * 32 + (i - 21)];
        }
        inp_s[ni][i] = v;
    }
    __syncthreads();
    float al = bl[k], ar = br[k];
    const float* wlr = &Wl_s[k * DIN];
    const float* wrr = &Wr_s[k * DIN];
#pragma unroll
    for (int i = 0; i < DIN; ++i) {
        float xv = inp_s[ni][i];
        al += xv * wlr[i];
        ar += xv * wrr[i];
    }
    xl[node * 32 + k] = al;
    xr[node * 32 + k] = ar;
}

// ---------------- GATv2 conv: one node per wave, 16 edge-groups x 4 lanes ----
// lane = g*4 + j : group g handles edges beg+g, beg+g+16, ...; lane slice j
// holds channels [j*8, j*8+8). Per-group online softmax, merged across the 16
// groups at the end (flash-attention-style rescale).
// ACT: 0 = sigmoid, 1 = tanh, 2 = relu
template <int ACT>
__global__ __launch_bounds__(256) void conv_kernel(const int* __restrict__ row_ptr,
                                                   const int* __restrict__ csr_src,
                                                   const float* __restrict__ xl,
                                                   const float* __restrict__ xr,
                                                   const float* __restrict__ att,
                                                   const float* __restrict__ bconv,
                                                   float* __restrict__ out) {
    int wid  = threadIdx.x >> 6;
    int lane = threadIdx.x & 63;
    int g = lane >> 2;
    int j = lane & 3;
    int n = blockIdx.x * 4 + wid;
    int c0 = j * 8;
    int beg = row_ptr[n], end = row_ptr[n + 1];

    float4 at0 = *(const float4*)(att + c0);
    float4 at1 = *(const float4*)(att + c0 + 4);
    float4 xr0 = *(const float4*)(xr + n * 32 + c0);
    float4 xr1 = *(const float4*)(xr + n * 32 + c0 + 4);

    float m = -INFINITY, den = 0.0f;
    float acc[8] = {0, 0, 0, 0, 0, 0, 0, 0};

    for (int p = beg + g; p < end; p += 16) {
        int s = csr_src[p];
        const float4* rp = (const float4*)(xl + s * 32 + c0);
        float4 v0 = rp[0];
        float4 v1 = rp[1];
        float part, z;
        z = v0.x + xr0.x; z = (z > 0.f) ? z : 0.2f * z; part  = z * at0.x;
        z = v0.y + xr0.y; z = (z > 0.f) ? z : 0.2f * z; part += z * at0.y;
        z = v0.z + xr0.z; z = (z > 0.f) ? z : 0.2f * z; part += z * at0.z;
        z = v0.w + xr0.w; z = (z > 0.f) ? z : 0.2f * z; part += z * at0.w;
        z = v1.x + xr1.x; z = (z > 0.f) ? z : 0.2f * z; part += z * at1.x;
        z = v1.y + xr1.y; z = (z > 0.f) ? z : 0.2f * z; part += z * at1.y;
        z = v1.z + xr1.z; z = (z > 0.f) ? z : 0.2f * z; part += z * at1.z;
        z = v1.w + xr1.w; z = (z > 0.f) ? z : 0.2f * z; part += z * at1.w;
        part += __shfl_xor(part, 1);
        part += __shfl_xor(part, 2);
        float e = part;
        if (e > m) {
            float sc = __expf(m - e);
            den *= sc;
#pragma unroll
            for (int i = 0; i < 8; ++i) acc[i] *= sc;
            m = e;
        }
        float a = __expf(e - m);
        den += a;
        acc[0] += a * v0.x; acc[1] += a * v0.y; acc[2] += a * v0.z; acc[3] += a * v0.w;
        acc[4] += a * v1.x; acc[5] += a * v1.y; acc[6] += a * v1.z; acc[7] += a * v1.w;
    }

    float o[8];
    if (beg < end) {
        float mt = m;
        mt = fmaxf(mt, __shfl_xor(mt, 4));
        mt = fmaxf(mt, __shfl_xor(mt, 8));
        mt = fmaxf(mt, __shfl_xor(mt, 16));
        mt = fmaxf(mt, __shfl_xor(mt, 32));
        float sc = __expf(m - mt);           // empty group: exp(-inf) = 0
        float d = den * sc;
        d += __shfl_xor(d, 4);
        d += __shfl_xor(d, 8);
        d += __shfl_xor(d, 16);
        d += __shfl_xor(d, 32);
#pragma unroll
        for (int i = 0; i < 8; ++i) {
            float t = acc[i] * sc;
            t += __shfl_xor(t, 4);
            t += __shfl_xor(t, 8);
            t += __shfl_xor(t, 16);
            t += __shfl_xor(t, 32);
            o[i] = t / d;                     // d >= 1 (max group contributes 1)
        }
    } else {
#pragma unroll
        for (int i = 0; i < 8; ++i) o[i] = 0.0f;
    }

    if (g == 0) {
        float4 bc0 = *(const float4*)(bconv + c0);
        float4 bc1 = *(const float4*)(bconv + c0 + 4);
        float r[8];
        r[0] = o[0] + bc0.x; r[1] = o[1] + bc0.y; r[2] = o[2] + bc0.z; r[3] = o[3] + bc0.w;
        r[4] = o[4] + bc1.x; r[5] = o[5] + bc1.y; r[6] = o[6] + bc1.z; r[7] = o[7] + bc1.w;
#pragma unroll
        for (int i = 0; i < 8; ++i) {
            if (ACT == 0)      r[i] = 1.0f / (1.0f + __expf(-r[i]));
            else if (ACT == 1) r[i] = tanhf(r[i]);
            else               r[i] = fmaxf(r[i], 0.0f);
        }
        float4* op = (float4*)(out + n * 32 + c0);
        op[0] = make_float4(r[0], r[1], r[2], r[3]);
        op[1] = make_float4(r[4], r[5], r[6], r[7]);
    }
}

// ---------------- hidden update + y1/x1 + dense for gate 3 ----------------
// ft2 = [x1(0..15), mask(16), hidden(17..48), labels(49..52)]

__global__ __launch_bounds__(256) void update_dense3_kernel(
        const float* __restrict__ g_update, const float* __restrict__ g_cell,
        float* __restrict__ hidden,
        const float* __restrict__ x_t, const float* __restrict__ mask,
        const float* __restrict__ labels,
        const float* __restrict__ W1, const float* __restrict__ b1,
        const float* __restrict__ Wl3, const float* __restrict__ bl3,
        const float* __restrict__ Wr3, const float* __restrict__ br3,
        float* __restrict__ xl, float* __restrict__ xr) {
    __shared__ float Wl_s[HID * DIN];
    __shared__ float Wr_s[HID * DIN];
    __shared__ float W1_s[FEAT * HID];
    __shared__ float inp_s[8][DIN];
    __shared__ float hs[8][HID + 1];
    for (int idx = threadIdx.x; idx < HID * DIN; idx += 256) {
        Wl_s[idx] = Wl3[idx];
        Wr_s[idx] = Wr3[idx];
    }
    for (int idx = threadIdx.x; idx < FEAT * HID; idx += 256) W1_s[idx] = W1[idx];
    int ni = threadIdx.x >> 5, k = threadIdx.x & 31;
    int node = blockIdx.x * 8 + ni;
    float u = g_update[node * 32 + k];
    float c = g_cell[node * 32 + k];
    float h = hidden[node * 32 + k];
    float hn = u * h + (1.0f - u) * c;
    hidden[node * 32 + k] = hn;
    hs[ni][k] = hn;
    inp_s[ni][17 + k] = hn;
    if (k == 0) inp_s[ni][16] = mask[node];
    if (k < 4)  inp_s[ni][49 + k] = labels[node * 4 + k];
    __syncthreads();
    if (k < 16) {
        float a = b1[k];
        const float* w = &W1_s[k * 32];
#pragma unroll
        for (int i = 0; i < 32; ++i) a += hs[ni][i] * w[i];
        float mv = mask[node];
        inp_s[ni][k] = (mv > 0.5f) ? x_t[node * 16 + k] : a;
    }
    __syncthreads();
    float al = bl3[k], ar = br3[k];
    const float* wl = &Wl_s[k * DIN];
    const float* wr = &Wr_s[k * DIN];
#pragma unroll
    for (int i = 0; i < DIN; ++i) {
        float xv = inp_s[ni][i];
        al += xv * wl[i];
        ar += xv * wr[i];
    }
    xl[node * 32 + k] = al;
    xr[node * 32 + k] = ar;
}

// ---------------- y2 / x2_new / out[t] ----------------

__global__ __launch_bounds__(256) void out_kernel(const float* __restrict__ s,
                                                  const float* __restrict__ hidden,
                                                  const float* __restrict__ W2,
                                                  const float* __restrict__ b2,
                                                  const float* __restrict__ x_t,
                                                  const float* __restrict__ mask,
                                                  float* __restrict__ x2,
                                                  float* __restrict__ out_t) {
    int ni = threadIdx.x >> 4, f = threadIdx.x & 15;
    int node = blockIdx.x * 16 + ni;
    float acc = b2[f];
    const float* srow = s + node * 32;
    const float* hrow = hidden + node * 32;
    const float* w = W2 + f * 64;
#pragma unroll
    for (int i = 0; i < 32; ++i) acc += srow[i] * w[i];
#pragma unroll
    for (int i = 0; i < 32; ++i) acc += hrow[i] * w[32 + i];
    float mv = mask[node];
    float xv = x_t[node * 16 + f];
    float r = (mv > 0.5f) ? xv : acc;
    x2[node * 16 + f] = r;
    out_t[node * 16 + f] = r;
}

// ---------------- launch ----------------

extern "C" void kernel_launch(void* const* d_in, const int* in_sizes, int n_in,
                              void* d_out, int out_size, void* d_ws, size_t ws_size,
                              hipStream_t stream) {
    const float* x      = (const float*)d_in[0];
    const float* mask   = (const float*)d_in[1];
    const float* labels = (const float*)d_in[2];
    const int*   src    = (const int*)d_in[3];
    const int*   dst    = src + EE;
    // d_in[4] = edge_weight: unused by the reference
    const float* Wl    = (const float*)d_in[5];
    const float* bl    = (const float*)d_in[6];
    const float* Wr    = (const float*)d_in[7];
    const float* br    = (const float*)d_in[8];
    const float* att   = (const float*)d_in[9];
    const float* bconv = (const float*)d_in[10];
    const float* W1    = (const float*)d_in[11];
    const float* b1    = (const float*)d_in[12];
    const float* W2    = (const float*)d_in[13];
    const float* b2    = (const float*)d_in[14];
    float* out = (float*)d_out;

    char* ws = (char*)d_ws;
    size_t off = 0;
    auto alloc = [&](size_t bytes) -> void* {
        void* p = ws + off;
        off = (off + bytes + 255) & ~(size_t)255;
        return p;
    };
    int*   row_ptr = (int*)alloc((NN + 1) * sizeof(int));
    int*   deg     = (int*)alloc(NN * sizeof(int));
    int*   csr_src = (int*)alloc(EE * sizeof(int));
    float* hidden  = (float*)alloc(NN * HID * sizeof(float));
    float* x2      = (float*)alloc(NN * FEAT * sizeof(float));
    float* xl      = (float*)alloc(NN * HID * sizeof(float));
    float* xr      = (float*)alloc(NN * HID * sizeof(float));
    float* g0      = (float*)alloc(NN * HID * sizeof(float));  // reset, later s
    float* g1      = (float*)alloc(NN * HID * sizeof(float));  // update
    float* g2      = (float*)alloc(NN * HID * sizeof(float));  // cell

    const int WD = HID * DIN;

    // CSR build (dst is identical for every conv, build once per call)
    zero_i32<<<(NN + 255) / 256, 256, 0, stream>>>(deg, NN);
    hist_kernel<<<EE / 256, 256, 0, stream>>>(dst, deg);
    scan_kernel<<<1, 1024, 0, stream>>>(deg, row_ptr);
    zero_i32<<<(NN + 255) / 256, 256, 0, stream>>>(deg, NN);
    scatter_kernel<<<EE / 256, 256, 0, stream>>>(src, dst, row_ptr, deg, csr_src);
    init_kernel<<<NN * HID / 256, 256, 0, stream>>>(x, mask, hidden, x2);

    for (int t = 0; t < TT; ++t) {
        const float* xt = x + (size_t)t * NN * FEAT;
        float* out_t = out + (size_t)t * NN * FEAT;
        // gate 0: reset = sigmoid(gatv2(inp))
        dense_kernel<false><<<NN / 8, 256, 0, stream>>>(x2, mask, labels, hidden, nullptr,
            Wl + 0 * WD, bl + 0 * HID, Wr + 0 * WD, br + 0 * HID, xl, xr);
        conv_kernel<0><<<NN / 4, 256, 0, stream>>>(row_ptr, csr_src, xl, xr,
            att + 0 * HID, bconv + 0 * HID, g0);
        // gate 1: update = sigmoid(gatv2(inp))
        dense_kernel<false><<<NN / 8, 256, 0, stream>>>(x2, mask, labels, hidden, nullptr,
            Wl + 1 * WD, bl + 1 * HID, Wr + 1 * WD, br + 1 * HID, xl, xr);
        conv_kernel<0><<<NN / 4, 256, 0, stream>>>(row_ptr, csr_src, xl, xr,
            att + 1 * HID, bconv + 1 * HID, g1);
        // gate 2: cell = tanh(gatv2(cin)), cin's h-part = reset*hidden
        dense_kernel<true><<<NN / 8, 256, 0, stream>>>(x2, mask, labels, hidden, g0,
            Wl + 2 * WD, bl + 2 * HID, Wr + 2 * WD, br + 2 * HID, xl, xr);
        conv_kernel<1><<<NN / 4, 256, 0, stream>>>(row_ptr, csr_src, xl, xr,
            att + 2 * HID, bconv + 2 * HID, g2);
        // hidden = u*h+(1-u)*c; y1; x1; dense for gate 3 (all node-local, fused)
        update_dense3_kernel<<<NN / 8, 256, 0, stream>>>(g1, g2, hidden, xt, mask, labels,
            W1, b1, Wl + 3 * WD, bl + 3 * HID, Wr + 3 * WD, br + 3 * HID, xl, xr);
        // gate 3: s = relu(gatv2(ft2))
        conv_kernel<2><<<NN / 4, 256, 0, stream>>>(row_ptr, csr_src, xl, xr,
            att + 3 * HID, bconv + 3 * HID, g0);
        // y2 = [s,hidden]@W2.T+b2; x2 = mask? x[t] : y2; out[t] = x2
        out_kernel<<<NN / 16, 256, 0, stream>>>(g0, hidden, W2, b2, xt, mask, x2, out_t);
    }
}